// Round 10
// baseline (403.817 us; speedup 1.0000x reference)
//
#include <hip/hip_runtime.h>
#include <stdint.h>

// LocalAttentionBlock: x[4,2048,2048] -> out[4,2048,2048] fp32
// cvt_all -> sincos table -> Q GEMM (256^2 8-phase) + KV GEMM (128x64) -> KV scatter
//   -> flash attn v8 (32x32 MFMA, 8 waves x 32q = 256-q blocks, in-register P) -> out GEMM

#define WIDTH_ 2048
#define NHEADS_ 16
#define HD_ 128
#define WINDOW_ 1024
#define B_ 4
#define T_ 2048
#define MROWS_ (B_ * T_)          // 8192
#define NQKV_ (WIDTH_ + 2 * HD_)  // 2304

typedef float f32x4 __attribute__((ext_vector_type(4)));
typedef float f32x16 __attribute__((ext_vector_type(16)));
typedef __bf16 bf16x8 __attribute__((ext_vector_type(8)));
typedef float f32x4v __attribute__((ext_vector_type(4)));
typedef unsigned short u16;
typedef unsigned int u32;

__device__ __forceinline__ u16 f2bf(float x) {
  u32 u = __builtin_bit_cast(u32, x);
  return (u16)((u + 0x7FFFu + ((u >> 16) & 1u)) >> 16);  // RNE
}
__device__ __forceinline__ float bf2f(u16 b) {
  u32 u = ((u32)b) << 16;
  return __builtin_bit_cast(float, u);
}
__device__ __forceinline__ u32 pack2bf(float a, float b) {
  union { __bf16 h[2]; u32 u; } c;
  c.h[0] = (__bf16)a; c.h[1] = (__bf16)b;
  return c.u;
}

__device__ __forceinline__ f32x4 mfma16(bf16x8 a, bf16x8 b, f32x4 c) {
  return __builtin_amdgcn_mfma_f32_16x16x32_bf16(a, b, c, 0, 0, 0);
}
__device__ __forceinline__ f32x16 mfma32(bf16x8 a, bf16x8 b, f32x16 c) {
  return __builtin_amdgcn_mfma_f32_32x32x16_bf16(a, b, c, 0, 0, 0);
}

#define GLL16(gp, lp)                                          \
  __builtin_amdgcn_global_load_lds(                            \
      (const __attribute__((address_space(1))) void*)(gp),     \
      (__attribute__((address_space(3))) void*)(lp), 16, 0, 0)

// 128^-0.5 * log2(e), folded into Q
#define CSC_ 0.12753101296631838f
#define L2C_ 0.4152410118609203f  // log2(10000)/32

// ---------------- fused fp32 -> bf16 convert (x + all weights) ----------------
__global__ __launch_bounds__(256) void cvt_all(const float* __restrict__ x,
                                               const float* __restrict__ wq,
                                               const float* __restrict__ wk,
                                               const float* __restrict__ wv,
                                               const float* __restrict__ wo,
                                               u16* __restrict__ xb,
                                               u16* __restrict__ wqkv,
                                               u16* __restrict__ wob) {
  const int NX = MROWS_ * WIDTH_ / 4;
  const int NQ = WIDTH_ * WIDTH_ / 4;
  const int NK = HD_ * WIDTH_ / 4;
  const int total = NX + 2 * NQ + 2 * NK;
  int i = blockIdx.x * blockDim.x + threadIdx.x;
  int stride = gridDim.x * blockDim.x;
  for (; i < total; i += stride) {
    const float* s;
    u16* d;
    int j;
    if (i < NX) { s = x; d = xb; j = i; }
    else if (i < NX + NQ) { s = wq; d = wqkv; j = i - NX; }
    else if (i < NX + NQ + NK) { s = wk; d = wqkv + (size_t)WIDTH_ * WIDTH_; j = i - NX - NQ; }
    else if (i < NX + NQ + 2 * NK) { s = wv; d = wqkv + (size_t)(WIDTH_ + HD_) * WIDTH_; j = i - NX - NQ - NK; }
    else { s = wo; d = wob; j = i - NX - NQ - 2 * NK; }
    f32x4v v = *reinterpret_cast<const f32x4v*>(s + 4 * (size_t)j);
    uint2 o;
    o.x = (u32)f2bf(v[0]) | ((u32)f2bf(v[1]) << 16);
    o.y = (u32)f2bf(v[2]) | ((u32)f2bf(v[3]) << 16);
    *reinterpret_cast<uint2*>(d + 4 * (size_t)j) = o;
  }
}

// ---------------- sincos table: sc[t][d] = (cos, sin)(pos_t * 10000^(-d/32)) ----------------
__global__ __launch_bounds__(256) void sincos_tab(const int* __restrict__ segpos,
                                                  float2* __restrict__ sc) {
  int idx = blockIdx.x * 256 + threadIdx.x;  // 65536 = 2048*32
  int t = idx >> 5, d = idx & 31;
  float pos = (float)segpos[t];
  float ang = pos * exp2f(-(float)d * L2C_);
  float2 v;
  v.x = cosf(ang);
  v.y = sinf(ang);
  sc[idx] = v;
}

// ---------------- GEMM: 128x64 tile (KV projection, 256 blocks) ----------------
__global__ __launch_bounds__(256) void gemm_bt64(const u16* __restrict__ A,
                                                 const u16* __restrict__ W,
                                                 u16* __restrict__ Cout,
                                                 int M, int N, int K) {
  __shared__ alignas(16) u16 As[128 * 32];
  __shared__ alignas(16) u16 Bs[64 * 32];
  const int tid = threadIdx.x;
  const int wid = tid >> 6, lane = tid & 63;
  const int g = lane >> 4, lr = lane & 15;
  const int m0 = blockIdx.y << 7, n0 = blockIdx.x << 6;
  const int wm = wid >> 1, wn = wid & 1;

  const f32x4 vzero = {0.f, 0.f, 0.f, 0.f};
  f32x4 acc[4][2];
#pragma unroll
  for (int i = 0; i < 4; i++)
#pragma unroll
    for (int j = 0; j < 2; j++) acc[i][j] = vzero;

  const int lrow = lane >> 2;
  const int lcol = (lane & 3) * 8;
  const u16* a0 = A + (size_t)(m0 + wid * 32 + lrow) * K + lcol;
  const u16* a1 = A + (size_t)(m0 + wid * 32 + 16 + lrow) * K + lcol;
  const u16* b0 = W + (size_t)(n0 + wid * 16 + lrow) * K + lcol;

  for (int k0 = 0; k0 < K; k0 += 32) {
    __syncthreads();
    GLL16(a0 + k0, &As[wid * 1024]);
    GLL16(a1 + k0, &As[wid * 1024 + 512]);
    GLL16(b0 + k0, &Bs[wid * 512]);
    __syncthreads();

    bf16x8 af[4], bfv[2];
#pragma unroll
    for (int mi = 0; mi < 4; mi++)
      af[mi] = *(const bf16x8*)&As[(wm * 64 + mi * 16 + lr) * 32 + g * 8];
#pragma unroll
    for (int ni = 0; ni < 2; ni++)
      bfv[ni] = *(const bf16x8*)&Bs[(wn * 32 + ni * 16 + lr) * 32 + g * 8];
#pragma unroll
    for (int mi = 0; mi < 4; mi++)
#pragma unroll
      for (int ni = 0; ni < 2; ni++)
        acc[mi][ni] = mfma16(af[mi], bfv[ni], acc[mi][ni]);
  }

#pragma unroll
  for (int mi = 0; mi < 4; mi++) {
    int row = m0 + wm * 64 + mi * 16 + g * 4;
#pragma unroll
    for (int ni = 0; ni < 2; ni++) {
      int col = n0 + wn * 32 + ni * 16 + lr;
#pragma unroll
      for (int r = 0; r < 4; r++)
        Cout[(size_t)(row + r) * N + col] = f2bf(acc[mi][ni][r]);
    }
  }
}

// ---------------- GEMM: 256x256 tile, BK=64, 8-phase dbuf ----------------
template <bool F32OUT>
__global__ __launch_bounds__(512, 2) void gemm256p8(const u16* __restrict__ A,
                                                    const u16* __restrict__ W,
                                                    void* __restrict__ Cout,
                                                    const float* __restrict__ bias,
                                                    int M, int N, int K) {
  __shared__ alignas(16) u16 As[2][2][128 * 64];
  __shared__ alignas(16) u16 Bs[2][2][128 * 64];
  const int tid = threadIdx.x;
  const int wid = tid >> 6, lane = tid & 63;
  const int g = lane >> 4, lr = lane & 15;
  const int wm = wid >> 2, wn = wid & 3;

  const int nwg = gridDim.x;
  const int o = blockIdx.x;
  const int wg = (o & 7) * (nwg >> 3) + (o >> 3);
  const int NT = N >> 8;
  const int mt = wg / NT, nt = wg % NT;
  const int m0 = mt << 8, n0 = nt << 8;

  const u16* pa[2];
  const u16* pb[2];
#pragma unroll
  for (int j = 0; j < 2; j++) {
    int ci = (wid + j * 8) * 64 + lane;
    int ri = ci >> 3, c = ci & 7;
    int colel = (c ^ (ri & 7)) * 8;
    int rA = ((ri >> 6) << 7) + (ri & 63);
    pa[j] = A + (size_t)(m0 + rA) * K + colel;
    pb[j] = W + (size_t)(n0 + ri) * K + colel;
  }
  const int dstoff = wid * 1024;

#define SA(bi, h, k0)                                                     \
  do {                                                                    \
    GLL16(pa[0] + (size_t)(h) * 64 * K + (k0), (char*)As[bi][h] + dstoff);\
    GLL16(pa[1] + (size_t)(h) * 64 * K + (k0),                            \
          (char*)As[bi][h] + dstoff + 8192);                              \
  } while (0)
#define SB(bi, h, k0)                                                     \
  do {                                                                    \
    GLL16(pb[0] + (size_t)(h) * 128 * K + (k0), (char*)Bs[bi][h] + dstoff);\
    GLL16(pb[1] + (size_t)(h) * 128 * K + (k0),                           \
          (char*)Bs[bi][h] + dstoff + 8192);                              \
  } while (0)

  const f32x4 vzero = {0.f, 0.f, 0.f, 0.f};
  f32x4 acc[8][4];
#pragma unroll
  for (int i = 0; i < 8; i++)
#pragma unroll
    for (int j = 0; j < 4; j++) acc[i][j] = vzero;

  bf16x8 bfv[4][2];

  auto LDA = [&](int bi, int mi, int kk) -> bf16x8 {
    int h = mi >> 2;
    int rb = wm * 64 + (mi & 3) * 16 + lr;
    return *(const bf16x8*)((const char*)As[bi][h] + rb * 128 +
                            (((kk * 4 + g) ^ (lr & 7)) << 4));
  };
  auto LDB = [&](int bi, int ni, int kk) -> bf16x8 {
    int rb = (wn & 1) * 64 + ni * 16 + lr;
    return *(const bf16x8*)((const char*)Bs[bi][wn >> 1] + rb * 128 +
                            (((kk * 4 + g) ^ (lr & 7)) << 4));
  };

#define VM6 asm volatile("s_waitcnt vmcnt(6)" ::: "memory")
#define VM0 asm volatile("s_waitcnt vmcnt(0)" ::: "memory")

#define PHASE(bi, p, STAGES, VM)                                          \
  {                                                                       \
    if ((p) == 0) {                                                       \
      for (int ni = 0; ni < 4; ni++)                                      \
        for (int kk = 0; kk < 2; kk++) bfv[ni][kk] = LDB(bi, ni, kk);     \
    }                                                                     \
    bf16x8 a0k0 = LDA(bi, 2 * (p), 0);                                    \
    bf16x8 a0k1 = LDA(bi, 2 * (p), 1);                                    \
    bf16x8 a1k0 = LDA(bi, 2 * (p) + 1, 0);                                \
    bf16x8 a1k1 = LDA(bi, 2 * (p) + 1, 1);                                \
    STAGES;                                                               \
    __builtin_amdgcn_s_barrier();                                         \
    asm volatile("s_waitcnt lgkmcnt(0)" ::: "memory");                    \
    __builtin_amdgcn_sched_barrier(0);                                    \
    __builtin_amdgcn_s_setprio(1);                                        \
    for (int ni = 0; ni < 4; ni++) {                                      \
      acc[2 * (p)][ni] = mfma16(a0k0, bfv[ni][0], acc[2 * (p)][ni]);      \
      acc[2 * (p)][ni] = mfma16(a0k1, bfv[ni][1], acc[2 * (p)][ni]);      \
      acc[2 * (p) + 1][ni] = mfma16(a1k0, bfv[ni][0], acc[2 * (p) + 1][ni]); \
      acc[2 * (p) + 1][ni] = mfma16(a1k1, bfv[ni][1], acc[2 * (p) + 1][ni]); \
    }                                                                     \
    __builtin_amdgcn_s_setprio(0);                                        \
    VM;                                                                   \
    __builtin_amdgcn_sched_barrier(0);                                    \
    __builtin_amdgcn_s_barrier();                                         \
  }

  SA(0, 0, 0); SA(0, 1, 0); SB(0, 0, 0); SB(0, 1, 0);
  SB(1, 0, 64); SB(1, 1, 64); SA(1, 0, 64);
  VM6;
  __builtin_amdgcn_sched_barrier(0);
  __builtin_amdgcn_s_barrier();

  const int half_iters = K >> 7;
  for (int i = 0; i < half_iters; ++i) {
    const bool pre = (i + 1 < half_iters);
    const int kc = i << 7;
    PHASE(0, 0, { SA(1, 1, kc + 64); }, );
    PHASE(0, 1, { if (pre) SB(0, 0, kc + 128); }, );
    PHASE(0, 2, { if (pre) SB(0, 1, kc + 128); }, );
    PHASE(0, 3, { if (pre) SA(0, 0, kc + 128); }, if (pre) { VM6; } else { VM0; });
    PHASE(1, 0, { if (pre) SA(0, 1, kc + 128); }, );
    PHASE(1, 1, { if (pre) SB(1, 0, kc + 192); }, );
    PHASE(1, 2, { if (pre) SB(1, 1, kc + 192); }, );
    PHASE(1, 3, { if (pre) SA(1, 0, kc + 192); }, if (pre) { VM6; } else { VM0; });
  }
#undef PHASE
#undef SA
#undef SB
#undef VM6
#undef VM0

#pragma unroll
  for (int mi = 0; mi < 8; mi++) {
    int row = m0 + wm * 128 + mi * 16 + g * 4;
#pragma unroll
    for (int ni = 0; ni < 4; ni++) {
      int col = n0 + wn * 64 + ni * 16 + lr;
#pragma unroll
      for (int r = 0; r < 4; r++) {
        float v = acc[mi][ni][r];
        if (F32OUT) {
          ((float*)Cout)[(size_t)(row + r) * N + col] = v + bias[col];
        } else {
          ((u16*)Cout)[(size_t)(row + r) * N + col] = f2bf(v);
        }
      }
    }
  }
}

// ---------------- KV scatter (K rope + V transpose) ----------------
__global__ __launch_bounds__(128) void kv_scatter(const u16* __restrict__ KVraw,
                                                  const int* __restrict__ segpos,
                                                  u16* __restrict__ Kb,
                                                  u16* __restrict__ VT) {
  const int row = blockIdx.x;  // b*T + t
  const int b = row / T_, t = row % T_;
  const float pos = (float)segpos[t];
  const u16* kvsrc = KVraw + (size_t)row * 256;
  const int tid = threadIdx.x;

  if (tid < 32) {
    int d = tid;
    float inv = exp2f(-(float)d * L2C_);
    float ang = pos * inv;
    float sn = sinf(ang), cs = cosf(ang);
    float x1 = bf2f(kvsrc[d]), x2 = bf2f(kvsrc[d + 32]);
    Kb[(size_t)row * HD_ + d] = f2bf(x1 * cs - x2 * sn);
    Kb[(size_t)row * HD_ + d + 32] = f2bf(x2 * cs + x1 * sn);
  } else if (tid >= 64 && tid < 128) {
    int d = tid;
    Kb[(size_t)row * HD_ + d] = kvsrc[d];
  }
  for (int j = tid; j < HD_; j += 128) {
    VT[((size_t)b * HD_ + j) * T_ + t] = kvsrc[HD_ + j];
  }
}

// ---------------- Flash attention v8: 32x32 MFMA, 8 waves x 32q (256-q block) ----------------
// Block: 256 q rows x 1 head, 8 waves x 32 q rows, 512 threads, 64KB LDS -> 2 blk/CU
// = 16 waves/CU. Same inner loop as v7 (swapped 32x32 QK^T, in-lane softmax,
// shfl_xor P exchange, no P LDS); staging split across 8 waves (4 chunks/lane).
__global__ __launch_bounds__(512, 4) void attn(const u16* __restrict__ Qraw,
                                               const float2* __restrict__ sc,
                                               const u16* __restrict__ Kb,
                                               const u16* __restrict__ VT,
                                               u16* __restrict__ Eb) {
  __shared__ alignas(16) u16 Ks[2][64 * 128];  // [s][d], 256B rows, 16-chunk swizzle
  __shared__ alignas(16) u16 Vs[2][128 * 64];  // [d][s], 128B rows, 8-chunk swizzle

  const int tid = threadIdx.x;
  const int wid = tid >> 6, lane = tid & 63;
  const int qc = lane & 31, hi = lane >> 5;

  const int bid = blockIdx.x;
  const int grp = bid >> 3;            // b*16 + n
  const int b = grp >> 4, n = grp & 15;
  const int qt = ((bid & 7) + b * 2) & 7;  // balance remap (bijective per b)
  const int q0b = qt * 256;
  const int q0w = q0b + wid * 32;
  const int q = q0w + qc;  // my q column

  const char* kptr = (const char*)(Kb + (size_t)b * T_ * HD_);
  const char* vptr = (const char*)(VT + (size_t)b * HD_ * T_);

  // staging: waves 0-3 -> K (4 rounds x 4 rows), waves 4-7 -> V (4 rounds x 8 rows)
  const char* srcb[4];
  int smul, dst0;
  if (wid < 4) {
    smul = HD_ * 2;  // bytes per s row
#pragma unroll
    for (int i = 0; i < 4; i++) {
      int row = wid * 16 + i * 4 + (lane >> 4);
      int c = (lane & 15) << 4;
      srcb[i] = kptr + (size_t)row * 256 + (c ^ ((row & 15) << 4));
    }
    dst0 = wid * 4096;
  } else {
    smul = 2;  // bytes per s col
#pragma unroll
    for (int i = 0; i < 4; i++) {
      int row = (wid - 4) * 32 + i * 8 + (lane >> 3);
      int c = (lane & 7) << 4;
      srcb[i] = vptr + (size_t)row * (T_ * 2) + (c ^ ((row & 7) << 4));
    }
    dst0 = (wid - 4) * 4096;
  }

  // Q B-frags: qf[st][j] = Qroped[q][d = st*16 + hi*8 + j] * CSC (rope via table)
  bf16x8 qf[8];
  {
    const u16* qp = Qraw + (size_t)(b * T_ + q) * WIDTH_ + n * HD_ + hi * 8;
    bf16x8 r[8];
#pragma unroll
    for (int s = 0; s < 8; s++) r[s] = *(const bf16x8*)(qp + s * 16);
    const float2* scp = sc + (size_t)q * 32 + hi * 8;
#pragma unroll
    for (int j = 0; j < 8; j++) {
      float2 c0 = scp[j];       // d = hi*8 + j
      float2 c1 = scp[16 + j];  // d = 16 + hi*8 + j
      float a1 = (float)r[0][j], a2 = (float)r[2][j];
      float b1 = (float)r[1][j], b2 = (float)r[3][j];
      qf[0][j] = (__bf16)((a1 * c0.x - a2 * c0.y) * CSC_);
      qf[2][j] = (__bf16)((a2 * c0.x + a1 * c0.y) * CSC_);
      qf[1][j] = (__bf16)((b1 * c1.x - b2 * c1.y) * CSC_);
      qf[3][j] = (__bf16)((b2 * c1.x + b1 * c1.y) * CSC_);
#pragma unroll
      for (int s = 4; s < 8; s++) qf[s][j] = (__bf16)((float)r[s][j] * CSC_);
    }
  }

  f32x16 eacc[4];
#pragma unroll
  for (int d = 0; d < 4; d++)
#pragma unroll
    for (int r = 0; r < 16; r++) eacc[d][r] = 0.f;
  float m_r = -1e30f, l_r = 0.f;  // per q-column (lane pair)

  const int sbeg = (q0b > WINDOW_) ? (q0b - WINDOW_) : 0;
  const int ntt = (q0b + 255 - sbeg) / 64 + 1;

  auto STAGE = [&](int s0, int buf) {
    char* dbase = (wid < 4) ? ((char*)Ks[buf] + dst0) : ((char*)Vs[buf] + dst0);
#pragma unroll
    for (int i = 0; i < 4; i++) {
      GLL16(srcb[i] + (size_t)s0 * smul, dbase + i * 1024);
    }
  };

  STAGE(sbeg, 0);
  __syncthreads();

  for (int t = 0; t < ntt; ++t) {
    const int s0 = sbeg + t * 64;
    const int cur = t & 1;
    if (t + 1 < ntt) STAGE(s0 + 64, cur ^ 1);

    const bool active = (s0 <= q0w + 31) && (s0 + 63 >= q0w - WINDOW_);
    if (active) {
      const char* kB = (const char*)Ks[cur];
      const char* vB = (const char*)Vs[cur];
      const bool wint = (s0 + 63 <= q0w) && (s0 >= q0w + 31 - WINDOW_);

      for (int sb = 0; sb < 2; sb++) {
        const int sblo = s0 + sb * 32;
        if (sblo > q0w + 31 || sblo + 31 < q0w - WINDOW_) continue;

        // ---- QK^T: sacc[r] = S[s = sblo + crow(r,hi)][q] ----
        f32x16 sacc;
#pragma unroll
        for (int r = 0; r < 16; r++) sacc[r] = 0.f;
        const int srow = sb * 32 + qc;
        const int kswz = (srow & 15) << 4;
#pragma unroll
        for (int st = 0; st < 8; st++) {
          bf16x8 kf = *(const bf16x8*)(kB + srow * 256 + ((st * 32 + hi * 16) ^ kswz));
          sacc = mfma32(kf, qf[st], sacc);
        }

        // ---- mask + in-lane max ----
        float p[16];
        float pm = -1e30f;
        if (wint) {
#pragma unroll
          for (int r = 0; r < 16; r++) {
            p[r] = sacc[r];
            pm = fmaxf(pm, p[r]);
          }
        } else {
#pragma unroll
          for (int r = 0; r < 16; r++) {
            int s = sblo + (r & 3) + 8 * (r >> 2) + 4 * hi;
            bool ok = (s <= q) && (s + WINDOW_ >= q);
            p[r] = ok ? sacc[r] : -1e30f;
            pm = fmaxf(pm, p[r]);
          }
        }
        pm = fmaxf(pm, __shfl_xor(pm, 32));

        // ---- defer-max online softmax ----
        if (!__all(pm <= m_r + 8.f)) {
          float mnew = fmaxf(m_r, pm);
          float alpha = exp2f(m_r - mnew);
          m_r = mnew;
          l_r *= alpha;
          float aq[16];
#pragma unroll
          for (int r = 0; r < 16; r++)
            aq[r] = __shfl(alpha, (r & 3) + 8 * (r >> 2) + 4 * hi);
#pragma unroll
          for (int d = 0; d < 4; d++)
#pragma unroll
            for (int r = 0; r < 16; r++) eacc[d][r] *= aq[r];
        }
        float rs = 0.f;
#pragma unroll
        for (int r = 0; r < 16; r++) {
          float e = exp2f(p[r] - m_r);
          p[r] = e;
          rs += e;
        }
        rs += __shfl_xor(rs, 32);
        l_r += rs;

        // ---- P -> PV A-frags (in-register, shfl_xor exchange) ----
        bf16x8 paf[2];
#pragma unroll
        for (int c = 0; c < 2; c++) {
          u32 wA = pack2bf(p[8 * c + 0], p[8 * c + 1]);
          u32 wB = pack2bf(p[8 * c + 2], p[8 * c + 3]);
          u32 wC = pack2bf(p[8 * c + 4], p[8 * c + 5]);
          u32 wD = pack2bf(p[8 * c + 6], p[8 * c + 7]);
          u32 xA = (u32)__shfl_xor((int)wA, 32);
          u32 xB = (u32)__shfl_xor((int)wB, 32);
          u32 xC = (u32)__shfl_xor((int)wC, 32);
          u32 xD = (u32)__shfl_xor((int)wD, 32);
          union { u32 w[4]; bf16x8 v; } af_;
          af_.w[0] = hi ? xC : wA;
          af_.w[1] = hi ? xD : wB;
          af_.w[2] = hi ? wC : xA;
          af_.w[3] = hi ? wD : xB;
          paf[c] = af_.v;
        }

        // ---- PV: eacc[dblk] += P * V (B-frag from VT rows) ----
#pragma unroll
        for (int d = 0; d < 4; d++) {
          const int vrow = d * 32 + qc;
          const int vs = ((vrow & 7) << 4);
#pragma unroll
          for (int c = 0; c < 2; c++) {
            int colb = (sb * 2 + c) * 32 + hi * 16;
            bf16x8 vf = *(const bf16x8*)(vB + vrow * 128 + (colb ^ vs));
            eacc[d] = mfma32(paf[c], vf, eacc[d]);
          }
        }
      }
    }
    __syncthreads();
  }

  // ---- normalize + store: eacc[d][r] is q-row q0w+crow(r,hi), col d*32+qc ----
  float linv = 1.f / l_r;
  float lqv[16];
#pragma unroll
  for (int r = 0; r < 16; r++)
    lqv[r] = __shfl(linv, (r & 3) + 8 * (r >> 2) + 4 * hi);
#pragma unroll
  for (int d = 0; d < 4; d++) {
#pragma unroll
    for (int r = 0; r < 16; r++) {
      int row = b * T_ + q0w + (r & 3) + 8 * (r >> 2) + 4 * hi;
      int col = n * HD_ + d * 32 + qc;
      Eb[(size_t)row * WIDTH_ + col] = f2bf(eacc[d][r] * lqv[r]);
    }
  }
}

// ---------------- launch ----------------
extern "C" void kernel_launch(void* const* d_in, const int* in_sizes, int n_in,
                              void* d_out, int out_size, void* d_ws, size_t ws_size,
                              hipStream_t stream) {
  (void)in_sizes; (void)n_in; (void)out_size; (void)ws_size;
  const float* x = (const float*)d_in[0];
  const int* segpos = (const int*)d_in[1];
  const float* wq = (const float*)d_in[3];
  const float* wk = (const float*)d_in[4];
  const float* wv = (const float*)d_in[5];
  const float* w_out = (const float*)d_in[6];
  const float* b_out = (const float*)d_in[7];

  char* p = (char*)d_ws;
  u16* xb = (u16*)p;    p += (size_t)MROWS_ * WIDTH_ * 2;
  u16* wqkv = (u16*)p;  p += (size_t)NQKV_ * WIDTH_ * 2;
  u16* wob = (u16*)p;   p += (size_t)WIDTH_ * WIDTH_ * 2;
  u16* qraw = (u16*)p;  p += (size_t)MROWS_ * WIDTH_ * 2;
  u16* kvraw = (u16*)p; p += (size_t)MROWS_ * 256 * 2;
  u16* kb = (u16*)p;    p += (size_t)MROWS_ * HD_ * 2;
  u16* vt = (u16*)p;    p += (size_t)B_ * HD_ * T_ * 2;
  float2* sc = (float2*)p; p += (size_t)T_ * 32 * 8;
  u16* eb = xb;  // alias: xb dead after Q/KV GEMMs

  cvt_all<<<4096, 256, 0, stream>>>(x, wq, wk, wv, w_out, xb, wqkv, wob);
  sincos_tab<<<T_ * 32 / 256, 256, 0, stream>>>(segpos, sc);

  gemm256p8<false><<<(MROWS_ / 256) * (WIDTH_ / 256), 512, 0, stream>>>(
      xb, wqkv, qraw, nullptr, MROWS_, WIDTH_, WIDTH_);
  gemm_bt64<<<dim3(256 / 64, MROWS_ / 128), 256, 0, stream>>>(
      xb, wqkv + (size_t)WIDTH_ * WIDTH_, kvraw, MROWS_, 256, WIDTH_);

  kv_scatter<<<MROWS_, 128, 0, stream>>>(kvraw, segpos, kb, vt);
  attn<<<B_ * NHEADS_ * (T_ / 256), 512, 0, stream>>>(qraw, sc, kb, vt, eb);

  gemm256p8<true><<<(MROWS_ / 256) * (WIDTH_ / 256), 512, 0, stream>>>(
      eb, wob, d_out, b_out, MROWS_, WIDTH_, WIDTH_);
}

// Round 11
// 306.824 us; speedup vs baseline: 1.3161x; 1.3161x over previous
//
#include <hip/hip_runtime.h>
#include <stdint.h>

// LocalAttentionBlock: x[4,2048,2048] -> out[4,2048,2048] fp32
// cvt_all -> Q GEMM (256^2 8-phase) + KV GEMM (128x64) -> KV scatter (+sincos tab)
//   -> flash attn v6 (table-based fused Q-RoPE, 8 waves x 16q) -> out GEMM (8-phase, +bias)

#define WIDTH_ 2048
#define NHEADS_ 16
#define HD_ 128
#define WINDOW_ 1024
#define B_ 4
#define T_ 2048
#define MROWS_ (B_ * T_)          // 8192
#define NQKV_ (WIDTH_ + 2 * HD_)  // 2304

typedef float f32x4 __attribute__((ext_vector_type(4)));
typedef __bf16 bf16x8 __attribute__((ext_vector_type(8)));
typedef float f32x4v __attribute__((ext_vector_type(4)));
typedef unsigned short u16;
typedef unsigned int u32;

__device__ __forceinline__ u16 f2bf(float x) {
  u32 u = __builtin_bit_cast(u32, x);
  return (u16)((u + 0x7FFFu + ((u >> 16) & 1u)) >> 16);  // RNE
}
__device__ __forceinline__ float bf2f(u16 b) {
  u32 u = ((u32)b) << 16;
  return __builtin_bit_cast(float, u);
}
__device__ __forceinline__ u32 pack2bf(float a, float b) {
  union { __bf16 h[2]; u32 u; } c;
  c.h[0] = (__bf16)a; c.h[1] = (__bf16)b;
  return c.u;
}

__device__ __forceinline__ f32x4 mfma16(bf16x8 a, bf16x8 b, f32x4 c) {
  return __builtin_amdgcn_mfma_f32_16x16x32_bf16(a, b, c, 0, 0, 0);
}

#define GLL16(gp, lp)                                          \
  __builtin_amdgcn_global_load_lds(                            \
      (const __attribute__((address_space(1))) void*)(gp),     \
      (__attribute__((address_space(3))) void*)(lp), 16, 0, 0)

// 128^-0.5 * log2(e), folded into Q
#define CSC_ 0.12753101296631838f
#define L2C_ 0.4152410118609203f  // log2(10000)/32

// ---------------- fused fp32 -> bf16 convert (x + all weights) ----------------
__global__ __launch_bounds__(256) void cvt_all(const float* __restrict__ x,
                                               const float* __restrict__ wq,
                                               const float* __restrict__ wk,
                                               const float* __restrict__ wv,
                                               const float* __restrict__ wo,
                                               u16* __restrict__ xb,
                                               u16* __restrict__ wqkv,
                                               u16* __restrict__ wob) {
  const int NX = MROWS_ * WIDTH_ / 4;
  const int NQ = WIDTH_ * WIDTH_ / 4;
  const int NK = HD_ * WIDTH_ / 4;
  const int total = NX + 2 * NQ + 2 * NK;
  int i = blockIdx.x * blockDim.x + threadIdx.x;
  int stride = gridDim.x * blockDim.x;
  for (; i < total; i += stride) {
    const float* s;
    u16* d;
    int j;
    if (i < NX) { s = x; d = xb; j = i; }
    else if (i < NX + NQ) { s = wq; d = wqkv; j = i - NX; }
    else if (i < NX + NQ + NK) { s = wk; d = wqkv + (size_t)WIDTH_ * WIDTH_; j = i - NX - NQ; }
    else if (i < NX + NQ + 2 * NK) { s = wv; d = wqkv + (size_t)(WIDTH_ + HD_) * WIDTH_; j = i - NX - NQ - NK; }
    else { s = wo; d = wob; j = i - NX - NQ - 2 * NK; }
    f32x4v v = *reinterpret_cast<const f32x4v*>(s + 4 * (size_t)j);
    uint2 o;
    o.x = (u32)f2bf(v[0]) | ((u32)f2bf(v[1]) << 16);
    o.y = (u32)f2bf(v[2]) | ((u32)f2bf(v[3]) << 16);
    *reinterpret_cast<uint2*>(d + 4 * (size_t)j) = o;
  }
}

// ---------------- GEMM: 128x64 tile (KV projection, 256 blocks) ----------------
__global__ __launch_bounds__(256) void gemm_bt64(const u16* __restrict__ A,
                                                 const u16* __restrict__ W,
                                                 u16* __restrict__ Cout,
                                                 int M, int N, int K) {
  __shared__ alignas(16) u16 As[128 * 32];
  __shared__ alignas(16) u16 Bs[64 * 32];
  const int tid = threadIdx.x;
  const int wid = tid >> 6, lane = tid & 63;
  const int g = lane >> 4, lr = lane & 15;
  const int m0 = blockIdx.y << 7, n0 = blockIdx.x << 6;
  const int wm = wid >> 1, wn = wid & 1;

  const f32x4 vzero = {0.f, 0.f, 0.f, 0.f};
  f32x4 acc[4][2];
#pragma unroll
  for (int i = 0; i < 4; i++)
#pragma unroll
    for (int j = 0; j < 2; j++) acc[i][j] = vzero;

  const int lrow = lane >> 2;
  const int lcol = (lane & 3) * 8;
  const u16* a0 = A + (size_t)(m0 + wid * 32 + lrow) * K + lcol;
  const u16* a1 = A + (size_t)(m0 + wid * 32 + 16 + lrow) * K + lcol;
  const u16* b0 = W + (size_t)(n0 + wid * 16 + lrow) * K + lcol;

  for (int k0 = 0; k0 < K; k0 += 32) {
    __syncthreads();
    GLL16(a0 + k0, &As[wid * 1024]);
    GLL16(a1 + k0, &As[wid * 1024 + 512]);
    GLL16(b0 + k0, &Bs[wid * 512]);
    __syncthreads();

    bf16x8 af[4], bfv[2];
#pragma unroll
    for (int mi = 0; mi < 4; mi++)
      af[mi] = *(const bf16x8*)&As[(wm * 64 + mi * 16 + lr) * 32 + g * 8];
#pragma unroll
    for (int ni = 0; ni < 2; ni++)
      bfv[ni] = *(const bf16x8*)&Bs[(wn * 32 + ni * 16 + lr) * 32 + g * 8];
#pragma unroll
    for (int mi = 0; mi < 4; mi++)
#pragma unroll
      for (int ni = 0; ni < 2; ni++)
        acc[mi][ni] = mfma16(af[mi], bfv[ni], acc[mi][ni]);
  }

#pragma unroll
  for (int mi = 0; mi < 4; mi++) {
    int row = m0 + wm * 64 + mi * 16 + g * 4;
#pragma unroll
    for (int ni = 0; ni < 2; ni++) {
      int col = n0 + wn * 32 + ni * 16 + lr;
#pragma unroll
      for (int r = 0; r < 4; r++)
        Cout[(size_t)(row + r) * N + col] = f2bf(acc[mi][ni][r]);
    }
  }
}

// ---------------- GEMM: 256x256 tile, BK=64, 8-phase dbuf ----------------
template <bool F32OUT>
__global__ __launch_bounds__(512, 2) void gemm256p8(const u16* __restrict__ A,
                                                    const u16* __restrict__ W,
                                                    void* __restrict__ Cout,
                                                    const float* __restrict__ bias,
                                                    int M, int N, int K) {
  __shared__ alignas(16) u16 As[2][2][128 * 64];
  __shared__ alignas(16) u16 Bs[2][2][128 * 64];
  const int tid = threadIdx.x;
  const int wid = tid >> 6, lane = tid & 63;
  const int g = lane >> 4, lr = lane & 15;
  const int wm = wid >> 2, wn = wid & 3;

  const int nwg = gridDim.x;
  const int o = blockIdx.x;
  const int wg = (o & 7) * (nwg >> 3) + (o >> 3);
  const int NT = N >> 8;
  const int mt = wg / NT, nt = wg % NT;
  const int m0 = mt << 8, n0 = nt << 8;

  const u16* pa[2];
  const u16* pb[2];
#pragma unroll
  for (int j = 0; j < 2; j++) {
    int ci = (wid + j * 8) * 64 + lane;
    int ri = ci >> 3, c = ci & 7;
    int colel = (c ^ (ri & 7)) * 8;
    int rA = ((ri >> 6) << 7) + (ri & 63);
    pa[j] = A + (size_t)(m0 + rA) * K + colel;
    pb[j] = W + (size_t)(n0 + ri) * K + colel;
  }
  const int dstoff = wid * 1024;

#define SA(bi, h, k0)                                                     \
  do {                                                                    \
    GLL16(pa[0] + (size_t)(h) * 64 * K + (k0), (char*)As[bi][h] + dstoff);\
    GLL16(pa[1] + (size_t)(h) * 64 * K + (k0),                            \
          (char*)As[bi][h] + dstoff + 8192);                              \
  } while (0)
#define SB(bi, h, k0)                                                     \
  do {                                                                    \
    GLL16(pb[0] + (size_t)(h) * 128 * K + (k0), (char*)Bs[bi][h] + dstoff);\
    GLL16(pb[1] + (size_t)(h) * 128 * K + (k0),                           \
          (char*)Bs[bi][h] + dstoff + 8192);                              \
  } while (0)

  const f32x4 vzero = {0.f, 0.f, 0.f, 0.f};
  f32x4 acc[8][4];
#pragma unroll
  for (int i = 0; i < 8; i++)
#pragma unroll
    for (int j = 0; j < 4; j++) acc[i][j] = vzero;

  bf16x8 bfv[4][2];

  auto LDA = [&](int bi, int mi, int kk) -> bf16x8 {
    int h = mi >> 2;
    int rb = wm * 64 + (mi & 3) * 16 + lr;
    return *(const bf16x8*)((const char*)As[bi][h] + rb * 128 +
                            (((kk * 4 + g) ^ (lr & 7)) << 4));
  };
  auto LDB = [&](int bi, int ni, int kk) -> bf16x8 {
    int rb = (wn & 1) * 64 + ni * 16 + lr;
    return *(const bf16x8*)((const char*)Bs[bi][wn >> 1] + rb * 128 +
                            (((kk * 4 + g) ^ (lr & 7)) << 4));
  };

#define VM6 asm volatile("s_waitcnt vmcnt(6)" ::: "memory")
#define VM0 asm volatile("s_waitcnt vmcnt(0)" ::: "memory")

#define PHASE(bi, p, STAGES, VM)                                          \
  {                                                                       \
    if ((p) == 0) {                                                       \
      for (int ni = 0; ni < 4; ni++)                                      \
        for (int kk = 0; kk < 2; kk++) bfv[ni][kk] = LDB(bi, ni, kk);     \
    }                                                                     \
    bf16x8 a0k0 = LDA(bi, 2 * (p), 0);                                    \
    bf16x8 a0k1 = LDA(bi, 2 * (p), 1);                                    \
    bf16x8 a1k0 = LDA(bi, 2 * (p) + 1, 0);                                \
    bf16x8 a1k1 = LDA(bi, 2 * (p) + 1, 1);                                \
    STAGES;                                                               \
    __builtin_amdgcn_s_barrier();                                         \
    asm volatile("s_waitcnt lgkmcnt(0)" ::: "memory");                    \
    __builtin_amdgcn_sched_barrier(0);                                    \
    __builtin_amdgcn_s_setprio(1);                                        \
    for (int ni = 0; ni < 4; ni++) {                                      \
      acc[2 * (p)][ni] = mfma16(a0k0, bfv[ni][0], acc[2 * (p)][ni]);      \
      acc[2 * (p)][ni] = mfma16(a0k1, bfv[ni][1], acc[2 * (p)][ni]);      \
      acc[2 * (p) + 1][ni] = mfma16(a1k0, bfv[ni][0], acc[2 * (p) + 1][ni]); \
      acc[2 * (p) + 1][ni] = mfma16(a1k1, bfv[ni][1], acc[2 * (p) + 1][ni]); \
    }                                                                     \
    __builtin_amdgcn_s_setprio(0);                                        \
    VM;                                                                   \
    __builtin_amdgcn_sched_barrier(0);                                    \
    __builtin_amdgcn_s_barrier();                                         \
  }

  SA(0, 0, 0); SA(0, 1, 0); SB(0, 0, 0); SB(0, 1, 0);
  SB(1, 0, 64); SB(1, 1, 64); SA(1, 0, 64);
  VM6;
  __builtin_amdgcn_sched_barrier(0);
  __builtin_amdgcn_s_barrier();

  const int half_iters = K >> 7;
  for (int i = 0; i < half_iters; ++i) {
    const bool pre = (i + 1 < half_iters);
    const int kc = i << 7;
    PHASE(0, 0, { SA(1, 1, kc + 64); }, );
    PHASE(0, 1, { if (pre) SB(0, 0, kc + 128); }, );
    PHASE(0, 2, { if (pre) SB(0, 1, kc + 128); }, );
    PHASE(0, 3, { if (pre) SA(0, 0, kc + 128); }, if (pre) { VM6; } else { VM0; });
    PHASE(1, 0, { if (pre) SA(0, 1, kc + 128); }, );
    PHASE(1, 1, { if (pre) SB(1, 0, kc + 192); }, );
    PHASE(1, 2, { if (pre) SB(1, 1, kc + 192); }, );
    PHASE(1, 3, { if (pre) SA(1, 0, kc + 192); }, if (pre) { VM6; } else { VM0; });
  }
#undef PHASE
#undef SA
#undef SB
#undef VM6
#undef VM0

#pragma unroll
  for (int mi = 0; mi < 8; mi++) {
    int row = m0 + wm * 128 + mi * 16 + g * 4;
#pragma unroll
    for (int ni = 0; ni < 4; ni++) {
      int col = n0 + wn * 64 + ni * 16 + lr;
#pragma unroll
      for (int r = 0; r < 4; r++) {
        float v = acc[mi][ni][r];
        if (F32OUT) {
          ((float*)Cout)[(size_t)(row + r) * N + col] = v + bias[col];
        } else {
          ((u16*)Cout)[(size_t)(row + r) * N + col] = f2bf(v);
        }
      }
    }
  }
}

// ---------------- KV scatter (K rope + V transpose) + sincos table ----------------
__global__ __launch_bounds__(128) void kv_scatter(const u16* __restrict__ KVraw,
                                                  const int* __restrict__ segpos,
                                                  u16* __restrict__ Kb,
                                                  u16* __restrict__ VT,
                                                  float2* __restrict__ sc) {
  const int row = blockIdx.x;  // b*T + t
  const int b = row / T_, t = row % T_;
  const float pos = (float)segpos[t];
  const u16* kvsrc = KVraw + (size_t)row * 256;
  const int tid = threadIdx.x;

  // sincos table: first 512 blocks compute 128 entries each (65536 = 2048*32)
  if (row < 512) {
    int idx = row * 128 + tid;
    int tt = idx >> 5, d = idx & 31;
    float ps = (float)segpos[tt];
    float ang = ps * exp2f(-(float)d * L2C_);
    float2 v;
    v.x = cosf(ang);
    v.y = sinf(ang);
    sc[idx] = v;
  }

  if (tid < 32) {
    int d = tid;
    float inv = exp2f(-(float)d * L2C_);
    float ang = pos * inv;
    float sn = sinf(ang), cs = cosf(ang);
    float x1 = bf2f(kvsrc[d]), x2 = bf2f(kvsrc[d + 32]);
    Kb[(size_t)row * HD_ + d] = f2bf(x1 * cs - x2 * sn);
    Kb[(size_t)row * HD_ + d + 32] = f2bf(x2 * cs + x1 * sn);
  } else if (tid >= 64 && tid < 128) {
    int d = tid;
    Kb[(size_t)row * HD_ + d] = kvsrc[d];
  }
  for (int j = tid; j < HD_; j += 128) {
    VT[((size_t)b * HD_ + j) * T_ + t] = kvsrc[HD_ + j];
  }
}

// ---------------- Flash attention v6 (fused Q-RoPE via table) ----------------
// Block: 128 q rows x 1 head, 8 waves x 16 q rows, 512 threads, 80KB LDS (2 blk/CU).
// Q read raw; RoPE applied in-register using the precomputed (cos,sin) table.
__global__ __launch_bounds__(512, 4) void attn(const u16* __restrict__ Qraw,
                                               const float2* __restrict__ sc,
                                               const u16* __restrict__ Kb,
                                               const u16* __restrict__ VT,
                                               u16* __restrict__ Eb) {
  __shared__ alignas(16) u16 Ks[2][64 * 128];  // [s][d] rows swizzled
  __shared__ alignas(16) u16 Vs[2][128 * 64];  // [d][s] rows swizzled
  __shared__ alignas(16) u16 Ps[8][16 * 64];   // per-wave P buffer

  const int tid = threadIdx.x;
  const int wid = tid >> 6, lane = tid & 63;
  const int g = lane >> 4, lr = lane & 15;

  const int bid = blockIdx.x;
  const int grp = bid >> 4;            // b*16 + n
  const int b = grp >> 4, n = grp & 15;
  const int qt = ((bid & 15) + b * 4) & 15;  // balance remap
  const int q0b = qt * 128;
  const int q0w = q0b + wid * 16;
  const int q = q0w + lr;

  const char* kptr = (const char*)(Kb + (size_t)b * T_ * HD_);
  const char* vptr = (const char*)(VT + (size_t)b * HD_ * T_);

  const char* srcb[4];
  int smul, dst0;
  if (wid < 4) {
    smul = HD_ * 2;
#pragma unroll
    for (int i = 0; i < 4; i++) {
      int row = wid * 16 + i * 4 + (lane >> 4);
      int c = (lane & 15) << 4;
      srcb[i] = kptr + (size_t)row * 256 + (c ^ ((row & 7) << 4));
    }
    dst0 = wid * 4096;
  } else {
    smul = 2;
#pragma unroll
    for (int i = 0; i < 4; i++) {
      int row = (wid - 4) * 32 + i * 8 + (lane >> 3);
      int c = (lane & 7) << 4;
      srcb[i] = vptr + (size_t)row * (T_ * 2) + (c ^ ((row & 7) << 4));
    }
    dst0 = (wid - 4) * 4096;
  }

  // Q fragments: load raw, RoPE + CSC via table
  bf16x8 qf[4];
  {
    const float2* scp = sc + (size_t)q * 32 + g * 8;
    const u16* qp = Qraw + (size_t)(b * T_ + q) * WIDTH_ + n * HD_;
    bf16x8 r0 = *(const bf16x8*)(qp + g * 8);
    bf16x8 r1 = *(const bf16x8*)(qp + 32 + g * 8);
    bf16x8 r2 = *(const bf16x8*)(qp + 64 + g * 8);
    bf16x8 r3 = *(const bf16x8*)(qp + 96 + g * 8);
#pragma unroll
    for (int j = 0; j < 8; j++) {
      float2 cs2 = scp[j];
      float x1 = (float)r0[j], x2 = (float)r1[j];
      qf[0][j] = (__bf16)((x1 * cs2.x - x2 * cs2.y) * CSC_);
      qf[1][j] = (__bf16)((x2 * cs2.x + x1 * cs2.y) * CSC_);
      qf[2][j] = (__bf16)((float)r2[j] * CSC_);
      qf[3][j] = (__bf16)((float)r3[j] * CSC_);
    }
  }

  const f32x4 vzero = {0.f, 0.f, 0.f, 0.f};
  f32x4 eacc[8];
#pragma unroll
  for (int i = 0; i < 8; i++) eacc[i] = vzero;
  float m_r = -1e30f, l_r = 0.f;  // per-lane, q-row = q

  const int sbeg = (q0b > WINDOW_) ? (q0b - WINDOW_) : 0;
  const int nt = (q0b + 127 - sbeg) / 64 + 1;

  char* Pw = (char*)Ps[wid];
  const int swz = (lr & 7) << 4;

  auto STAGE = [&](int s0, int buf) {
    char* dbase = (wid < 4) ? ((char*)Ks[buf] + dst0) : ((char*)Vs[buf] + dst0);
#pragma unroll
    for (int i = 0; i < 4; i++) {
      GLL16(srcb[i] + (size_t)s0 * smul, dbase + i * 1024);
    }
  };

  STAGE(sbeg, 0);
  __syncthreads();

  for (int t = 0; t < nt; ++t) {
    const int s0 = sbeg + t * 64;
    const int cur = t & 1;
    if (t + 1 < nt) STAGE(s0 + 64, cur ^ 1);

    const bool active = (s0 <= q0w + 15) && (s0 + 63 >= q0w - WINDOW_);
    if (active) {
      const char* kB = (const char*)Ks[cur];
      const char* vB = (const char*)Vs[cur];
      f32x4 sacc[4];
#pragma unroll
      for (int h = 0; h < 4; h++) sacc[h] = vzero;
#pragma unroll
      for (int h = 0; h < 4; h++) {
        const int krow = h * 16 + lr;
#pragma unroll
        for (int kk = 0; kk < 4; kk++) {
          bf16x8 kf = *(const bf16x8*)(kB + krow * 256 + ((kk * 64 + g * 16) ^ swz));
          sacc[h] = mfma16(kf, qf[kk], sacc[h]);
        }
      }

      const bool wint = (s0 + 63 <= q0w) && (s0 >= q0w + 15 - WINDOW_);
      float pm = -1e30f;
      if (wint) {
#pragma unroll
        for (int h = 0; h < 4; h++)
#pragma unroll
          for (int r = 0; r < 4; r++) pm = fmaxf(pm, sacc[h][r]);
      } else {
#pragma unroll
        for (int h = 0; h < 4; h++)
#pragma unroll
          for (int r = 0; r < 4; r++) {
            int s = s0 + h * 16 + g * 4 + r;
            bool ok = (s <= q) && (s + WINDOW_ >= q);
            float v = ok ? sacc[h][r] : -1e30f;
            sacc[h][r] = v;
            pm = fmaxf(pm, v);
          }
      }
      pm = fmaxf(pm, __shfl_xor(pm, 16));
      pm = fmaxf(pm, __shfl_xor(pm, 32));

      if (!__all(pm <= m_r + 8.f)) {
        float mnew = fmaxf(m_r, pm);
        float alpha = exp2f(m_r - mnew);
        m_r = mnew;
        l_r *= alpha;
        float aq[4];
#pragma unroll
        for (int r = 0; r < 4; r++) aq[r] = __shfl(alpha, g * 4 + r);
#pragma unroll
        for (int i = 0; i < 8; i++) {
          f32x4 e = eacc[i];
#pragma unroll
          for (int r = 0; r < 4; r++) e[r] *= aq[r];
          eacc[i] = e;
        }
      }
      float rs = 0.f;
#pragma unroll
      for (int h = 0; h < 4; h++)
#pragma unroll
        for (int r = 0; r < 4; r++) {
          float e = exp2f(sacc[h][r] - m_r);
          sacc[h][r] = e;
          rs += e;
        }
      rs += __shfl_xor(rs, 16);
      rs += __shfl_xor(rs, 32);
      l_r += rs;

#pragma unroll
      for (int h = 0; h < 4; h++) {
        int base = (lr * 128 + h * 32 + g * 8) ^ swz;
        uint2 w2;
        w2.x = pack2bf(sacc[h][0], sacc[h][1]);
        w2.y = pack2bf(sacc[h][2], sacc[h][3]);
        *(uint2*)(Pw + base) = w2;
      }
      bf16x8 pf0 = *(const bf16x8*)(Pw + ((lr * 128 + g * 16) ^ swz));
      bf16x8 pf1 = *(const bf16x8*)(Pw + ((lr * 128 + 64 + g * 16) ^ swz));

#pragma unroll
      for (int ht = 0; ht < 8; ht++) {
        const int vrow = ht * 16 + lr;
        bf16x8 vf0 = *(const bf16x8*)(vB + vrow * 128 + ((g * 16) ^ swz));
        bf16x8 vf1 = *(const bf16x8*)(vB + vrow * 128 + ((64 + g * 16) ^ swz));
        eacc[ht] = mfma16(pf0, vf0, eacc[ht]);
        eacc[ht] = mfma16(pf1, vf1, eacc[ht]);
      }
    }
    __syncthreads();
  }

  float lq[4];
#pragma unroll
  for (int r = 0; r < 4; r++) lq[r] = 1.f / __shfl(l_r, g * 4 + r);
#pragma unroll
  for (int ht = 0; ht < 8; ht++) {
#pragma unroll
    for (int r = 0; r < 4; r++) {
      int row = b * T_ + q0w + g * 4 + r;
      int col = n * HD_ + ht * 16 + lr;
      Eb[(size_t)row * WIDTH_ + col] = f2bf(eacc[ht][r] * lq[r]);
    }
  }
}

// ---------------- launch ----------------
extern "C" void kernel_launch(void* const* d_in, const int* in_sizes, int n_in,
                              void* d_out, int out_size, void* d_ws, size_t ws_size,
                              hipStream_t stream) {
  (void)in_sizes; (void)n_in; (void)out_size; (void)ws_size;
  const float* x = (const float*)d_in[0];
  const int* segpos = (const int*)d_in[1];
  const float* wq = (const float*)d_in[3];
  const float* wk = (const float*)d_in[4];
  const float* wv = (const float*)d_in[5];
  const float* w_out = (const float*)d_in[6];
  const float* b_out = (const float*)d_in[7];

  char* p = (char*)d_ws;
  u16* xb = (u16*)p;    p += (size_t)MROWS_ * WIDTH_ * 2;
  u16* wqkv = (u16*)p;  p += (size_t)NQKV_ * WIDTH_ * 2;
  u16* wob = (u16*)p;   p += (size_t)WIDTH_ * WIDTH_ * 2;
  u16* qraw = (u16*)p;  p += (size_t)MROWS_ * WIDTH_ * 2;
  u16* kvraw = (u16*)p; p += (size_t)MROWS_ * 256 * 2;
  u16* kb = (u16*)p;    p += (size_t)MROWS_ * HD_ * 2;
  u16* vt = (u16*)p;    p += (size_t)B_ * HD_ * T_ * 2;
  float2* sc = (float2*)p; p += (size_t)T_ * 32 * 8;
  u16* eb = xb;  // alias: xb dead after Q/KV GEMMs

  cvt_all<<<4096, 256, 0, stream>>>(x, wq, wk, wv, w_out, xb, wqkv, wob);

  gemm256p8<false><<<(MROWS_ / 256) * (WIDTH_ / 256), 512, 0, stream>>>(
      xb, wqkv, qraw, nullptr, MROWS_, WIDTH_, WIDTH_);
  gemm_bt64<<<dim3(256 / 64, MROWS_ / 128), 256, 0, stream>>>(
      xb, wqkv + (size_t)WIDTH_ * WIDTH_, kvraw, MROWS_, 256, WIDTH_);

  kv_scatter<<<MROWS_, 128, 0, stream>>>(kvraw, segpos, kb, vt, sc);
  attn<<<B_ * NHEADS_ * (T_ / 128), 512, 0, stream>>>(qraw, sc, kb, vt, eb);

  gemm256p8<true><<<(MROWS_ / 256) * (WIDTH_ / 256), 512, 0, stream>>>(
      eb, wob, d_out, b_out, MROWS_, WIDTH_, WIDTH_);
}